// Round 1
// baseline (221.508 us; speedup 1.0000x reference)
//
#include <hip/hip_runtime.h>
#include <math.h>

#define LOG2E 1.4426950408889634f

__device__ __forceinline__ float rl(float v, int lane) {
  return __builtin_bit_cast(float, __builtin_amdgcn_readlane(__builtin_bit_cast(int, v), lane));
}
template<int CTRL>
__device__ __forceinline__ float dppb(float x) {
  return __builtin_bit_cast(float, __builtin_amdgcn_update_dpp(
      0, __builtin_bit_cast(int, x), CTRL, 0xF, 0xF, true));
}
__device__ __forceinline__ float fexp2(float x){ return __builtin_amdgcn_exp2f(x); }
__device__ __forceinline__ float frcp(float x){ return __builtin_amdgcn_rcpf(x); }
__device__ __forceinline__ float sigm(float x){ return frcp(1.f + fexp2(-LOG2E*x)); }
__device__ __forceinline__ float tanhf_(float x){ return fmaf(frcp(1.f + fexp2(-2.f*LOG2E*x)), 2.f, -1.f); }

// ---------------------------------------------------------------------------
// Kernel 1: scene biLSTM (8 steps, hidden 10) + a0 + packed pose array.
// One block (1 wave) per batch element; quad-lane layout: lane 4k+q = gate q
// of hidden unit k. Nonlinearity scale folded into weights (m = -log2e or
// -2log2e): s = rcp(1+exp2(g_scaled)) then fma(s, a, b) gives sigmoid/tanh.
// ---------------------------------------------------------------------------
__global__ __launch_bounds__(64) void scene_kernel(
    const float* __restrict__ scene,
    const float* __restrict__ nw_f, const float* __restrict__ nu_f,
    const float* __restrict__ nbi_f, const float* __restrict__ nbh_f,
    const float* __restrict__ nw_b, const float* __restrict__ nu_b,
    const float* __restrict__ nbi_b, const float* __restrict__ nbh_b,
    const float* __restrict__ aw, const float* __restrict__ ab,
    float* __restrict__ catted, float* __restrict__ a0, float* __restrict__ pose2)
{
  const int b = blockIdx.x;
  const int l = threadIdx.x;
  if (l < 2) {
    pose2[b*2 + l] = scene[b*32 + 28 + l];
    float acc = ab[l];
    #pragma unroll
    for (int jj = 0; jj < 4; jj++) acc = fmaf(scene[b*32 + 28 + jj], aw[l*4 + jj], acc);
    a0[b*2 + l] = acc;
  }
  const int k = l >> 2, q = l & 3;
  const int row = (l < 40) ? (q*10 + k) : 0;
  const float m  = (q == 2) ? (-2.f*LOG2E) : (-LOG2E);
  const float aa = (q == 2) ? 2.f : 1.f;
  const float bb = (q == 2) ? -1.f : 0.f;
  #pragma unroll
  for (int dir = 0; dir < 2; dir++) {
    const float* W  = dir ? nw_b  : nw_f;
    const float* U  = dir ? nu_b  : nu_f;
    const float* BI = dir ? nbi_b : nbi_f;
    const float* BH = dir ? nbh_b : nbh_f;
    float wi[4], wh[10];
    #pragma unroll
    for (int jj = 0; jj < 4; jj++)  wi[jj] = W[row*4 + jj] * m;
    #pragma unroll
    for (int jj = 0; jj < 10; jj++) wh[jj] = U[row*10 + jj] * m;
    const float cst = (BI[row] + BH[row]) * m;
    float c = 0.f, h = 0.f;
    for (int tt = 0; tt < 8; tt++) {
      const int t = dir ? (7 - tt) : tt;
      const float4 x = *(const float4*)(scene + b*32 + t*4);
      float g0 = fmaf(x.x, wi[0], cst);
      float g1 = x.y * wi[1];
      g0 = fmaf(x.z, wi[2], g0);
      g1 = fmaf(x.w, wi[3], g1);
      #pragma unroll
      for (int kk = 0; kk < 10; kk++) {
        const float hk = rl(h, 4*kk);
        if (kk & 1) g1 = fmaf(hk, wh[kk], g1); else g0 = fmaf(hk, wh[kk], g0);
      }
      float s = fmaf(frcp(1.f + fexp2(g0 + g1)), aa, bb);
      const float si = dppb<0x00>(s);
      const float sf = dppb<0x55>(s);
      const float tg = dppb<0xAA>(s);
      const float so = dppb<0xFF>(s);
      c = fmaf(sf, c, si*tg);
      h = so * tanhf_(c);
      if (q == 0 && l < 40) catted[b*180 + t*20 + dir*10 + k] = h;
    }
  }
}

// ---------------------------------------------------------------------------
// Kernel 2: edge-LSTM. THE critical path: 1024 sequential steps per batch
// element. One wave per batch element (1024 waves = 1/SIMD chip-wide).
// deltas[i,j] = pose[j]-pose[i] => fold -pose[i]*W + biases into a constant;
// per step only pose[j]*W is added (pose staged in LDS, uniform broadcast).
// Backward direction at t=-1 is a single LSTM step (epilogue).
// ---------------------------------------------------------------------------
__global__ __launch_bounds__(64) void edge_kernel(
    const float* __restrict__ scene,
    const float* __restrict__ ew_f, const float* __restrict__ eu_f,
    const float* __restrict__ ebi_f, const float* __restrict__ ebh_f,
    const float* __restrict__ ew_b, const float* __restrict__ eu_b,
    const float* __restrict__ ebi_b, const float* __restrict__ ebh_b,
    const float* __restrict__ pose2, float* __restrict__ catted)
{
  __shared__ float2 pbuf[1024];
  const int b = blockIdx.x;
  const int l = threadIdx.x;
  const float2* p2 = (const float2*)pose2;
  for (int t = l; t < 1024; t += 64) pbuf[t] = p2[t];

  const int k = l >> 2, q = l & 3;
  const int row = (l < 40) ? (q*10 + k) : 0;
  const float m  = (q == 2) ? (-2.f*LOG2E) : (-LOG2E);
  const float aa = (q == 2) ? 2.f : 1.f;
  const float bb = (q == 2) ? -1.f : 0.f;
  const float pix = scene[b*32 + 28], piy = scene[b*32 + 29];
  const float wxs = ew_f[row*2]   * m;
  const float wys = ew_f[row*2+1] * m;
  float wh[10];
  #pragma unroll
  for (int jj = 0; jj < 10; jj++) wh[jj] = eu_f[row*10 + jj] * m;
  const float cst = fmaf(-pix, wxs, fmaf(-piy, wys, (ebi_f[row] + ebh_f[row]) * m));
  float c = 0.f, h = 0.f;
  __syncthreads();
  #pragma unroll 2
  for (int j = 0; j < 1024; j++) {
    const float2 pj = pbuf[j];
    float g0 = fmaf(pj.x, wxs, cst);
    float g1 = pj.y * wys;
    #pragma unroll
    for (int kk = 0; kk < 10; kk++) {
      const float hk = rl(h, 4*kk);
      if (kk & 1) g1 = fmaf(hk, wh[kk], g1); else g0 = fmaf(hk, wh[kk], g0);
    }
    float s = fmaf(frcp(1.f + fexp2(g0 + g1)), aa, bb);
    const float si = dppb<0x00>(s);
    const float sf = dppb<0x55>(s);
    const float tg = dppb<0xAA>(s);
    const float so = dppb<0xFF>(s);
    c = fmaf(sf, c, si*tg);
    h = so * tanhf_(c);
  }
  // backward direction, single step from zero state on deltas[:, -1]
  const float wxb = ew_b[row*2] * m, wyb = ew_b[row*2+1] * m;
  const float cstb = (ebi_b[row] + ebh_b[row]) * m;
  const float2 pl = pbuf[1023];
  const float gB = fmaf(pl.x - pix, wxb, fmaf(pl.y - piy, wyb, cstb));
  float sB = fmaf(frcp(1.f + fexp2(gB)), aa, bb);
  const float siB = dppb<0x00>(sB);
  const float tgB = dppb<0xAA>(sB);
  const float soB = dppb<0xFF>(sB);
  const float cB = siB * tgB;
  const float hB = soB * tanhf_(cB);
  if (q == 0 && l < 40) {
    catted[b*180 + 160 + k] = h;
    catted[b*180 + 170 + k] = hB;
  }
}

// ---------------------------------------------------------------------------
// Kernel 3: GRU scan (12 steps) + heads + sampling. Per-batch independent:
// 4 batch elems per block, 384 threads (gate j per thread), gu row held in
// 128 VGPRs across all 12 steps. Gc = catted@gw[:, :180].T + gbi hoisted.
// ---------------------------------------------------------------------------
#define GBPB 4
__global__ __launch_bounds__(384) void gru_kernel(
    const float* __restrict__ catted, const float* __restrict__ a0,
    const float* __restrict__ eps,
    const float* __restrict__ gw, const float* __restrict__ gu,
    const float* __restrict__ gbi, const float* __restrict__ gbh,
    const float* __restrict__ sw, const float* __restrict__ sb,
    const float* __restrict__ pw, const float* __restrict__ pb,
    const float* __restrict__ mw, const float* __restrict__ mb,
    const float* __restrict__ lw, const float* __restrict__ lb,
    const float* __restrict__ cw, const float* __restrict__ cb,
    float* __restrict__ out)
{
  __shared__ float cat4[GBPB][180];
  __shared__ float h4[128][GBPB];
  __shared__ float gi4[384][GBPB];
  __shared__ float gh4[384][GBPB];
  __shared__ float head6[6][GBPB];
  __shared__ float a_l[GBPB][2];
  const int j = threadIdx.x;
  const int b0 = blockIdx.x * GBPB;

  {
    float* cf = &cat4[0][0];
    for (int idx = j; idx < GBPB*180; idx += 384) cf[idx] = catted[b0*180 + idx];
  }
  if (j < GBPB*2) a_l[j >> 1][j & 1] = a0[b0*2 + j];
  __syncthreads();

  float Gc[GBPB];
  {
    const float gbij = gbi[j];
    #pragma unroll
    for (int bb2 = 0; bb2 < GBPB; bb2++) Gc[bb2] = gbij;
  }
  const float* gwr = gw + j*182;
  for (int kk = 0; kk < 180; kk += 2) {
    const float2 w2 = *(const float2*)(gwr + kk);
    #pragma unroll
    for (int bb2 = 0; bb2 < GBPB; bb2++)
      Gc[bb2] = fmaf(w2.x, cat4[bb2][kk], fmaf(w2.y, cat4[bb2][kk+1], Gc[bb2]));
  }
  const float gwa0 = gwr[180], gwa1 = gwr[181];
  const float gbhj = gbh[j];

  float4 gur[32];
  {
    const float4* gup = (const float4*)(gu + j*128);
    #pragma unroll
    for (int kk = 0; kk < 32; kk++) gur[kk] = gup[kk];
  }

  const int w = j >> 6, lane = j & 63;
  float hwlo, hwhi, hbias;
  if      (w == 0) { hwlo = pw[lane];     hwhi = pw[64+lane];  hbias = pb[0]; }
  else if (w == 1) { hwlo = mw[lane];     hwhi = mw[64+lane];  hbias = mb[0]; }
  else if (w == 2) { hwlo = mw[128+lane]; hwhi = mw[192+lane]; hbias = mb[1]; }
  else if (w == 3) { hwlo = lw[lane];     hwhi = lw[64+lane];  hbias = lb[0]; }
  else if (w == 4) { hwlo = lw[128+lane]; hwhi = lw[192+lane]; hbias = lb[1]; }
  else             { hwlo = cw[lane];     hwhi = cw[64+lane];  hbias = cb[0]; }

  if (j < 128) {  // state0 = catted @ sw.T + sb
    const float* swr = sw + j*180;
    float s0[GBPB];
    const float sbj = sb[j];
    #pragma unroll
    for (int bb2 = 0; bb2 < GBPB; bb2++) s0[bb2] = sbj;
    for (int kk = 0; kk < 180; kk += 2) {
      const float2 w2 = *(const float2*)(swr + kk);
      #pragma unroll
      for (int bb2 = 0; bb2 < GBPB; bb2++)
        s0[bb2] = fmaf(w2.x, cat4[bb2][kk], fmaf(w2.y, cat4[bb2][kk+1], s0[bb2]));
    }
    *(float4*)&h4[j][0] = make_float4(s0[0], s0[1], s0[2], s0[3]);
  }
  __syncthreads();

  for (int t = 0; t < 12; t++) {
    float giv[GBPB], ghv[GBPB];
    #pragma unroll
    for (int bb2 = 0; bb2 < GBPB; bb2++) {
      giv[bb2] = fmaf(gwa0, a_l[bb2][0], fmaf(gwa1, a_l[bb2][1], Gc[bb2]));
      ghv[bb2] = gbhj;
    }
    #pragma unroll
    for (int kk = 0; kk < 32; kk++) {
      const float4 wv = gur[kk];
      const float4* hp = (const float4*)&h4[kk*4][0];
      const float4 ha = hp[0], hb = hp[1], hc = hp[2], hd = hp[3];
      ghv[0] = fmaf(wv.x, ha.x, ghv[0]); ghv[1] = fmaf(wv.x, ha.y, ghv[1]);
      ghv[2] = fmaf(wv.x, ha.z, ghv[2]); ghv[3] = fmaf(wv.x, ha.w, ghv[3]);
      ghv[0] = fmaf(wv.y, hb.x, ghv[0]); ghv[1] = fmaf(wv.y, hb.y, ghv[1]);
      ghv[2] = fmaf(wv.y, hb.z, ghv[2]); ghv[3] = fmaf(wv.y, hb.w, ghv[3]);
      ghv[0] = fmaf(wv.z, hc.x, ghv[0]); ghv[1] = fmaf(wv.z, hc.y, ghv[1]);
      ghv[2] = fmaf(wv.z, hc.z, ghv[2]); ghv[3] = fmaf(wv.z, hc.w, ghv[3]);
      ghv[0] = fmaf(wv.w, hd.x, ghv[0]); ghv[1] = fmaf(wv.w, hd.y, ghv[1]);
      ghv[2] = fmaf(wv.w, hd.z, ghv[2]); ghv[3] = fmaf(wv.w, hd.w, ghv[3]);
    }
    *(float4*)&gi4[j][0] = make_float4(giv[0], giv[1], giv[2], giv[3]);
    *(float4*)&gh4[j][0] = make_float4(ghv[0], ghv[1], ghv[2], ghv[3]);
    __syncthreads();

    if (j < 128) {
      const float4 gir = *(const float4*)&gi4[j][0];
      const float4 ghr = *(const float4*)&gh4[j][0];
      const float4 giz = *(const float4*)&gi4[128+j][0];
      const float4 ghz = *(const float4*)&gh4[128+j][0];
      const float4 gin = *(const float4*)&gi4[256+j][0];
      const float4 ghn = *(const float4*)&gh4[256+j][0];
      const float4 hold = *(const float4*)&h4[j][0];
      float hn0, hn1, hn2, hn3;
      { const float r = sigm(gir.x + ghr.x), z = sigm(giz.x + ghz.x);
        const float n = tanhf_(fmaf(r, ghn.x, gin.x));
        hn0 = fmaf(z, hold.x - n, n); }
      { const float r = sigm(gir.y + ghr.y), z = sigm(giz.y + ghz.y);
        const float n = tanhf_(fmaf(r, ghn.y, gin.y));
        hn1 = fmaf(z, hold.y - n, n); }
      { const float r = sigm(gir.z + ghr.z), z = sigm(giz.z + ghz.z);
        const float n = tanhf_(fmaf(r, ghn.z, gin.z));
        hn2 = fmaf(z, hold.z - n, n); }
      { const float r = sigm(gir.w + ghr.w), z = sigm(giz.w + ghz.w);
        const float n = tanhf_(fmaf(r, ghn.w, gin.w));
        hn3 = fmaf(z, hold.w - n, n); }
      *(float4*)&h4[j][0] = make_float4(hn0, hn1, hn2, hn3);
    }
    __syncthreads();

    {  // heads: wave w computes head w for all 4 batches via shuffle reduce
      const float4 hlo = *(const float4*)&h4[lane][0];
      const float4 hhi = *(const float4*)&h4[64+lane][0];
      float v0 = fmaf(hwlo, hlo.x, hwhi*hhi.x);
      float v1 = fmaf(hwlo, hlo.y, hwhi*hhi.y);
      float v2 = fmaf(hwlo, hlo.z, hwhi*hhi.z);
      float v3 = fmaf(hwlo, hlo.w, hwhi*hhi.w);
      #pragma unroll
      for (int off = 32; off > 0; off >>= 1) {
        v0 += __shfl_xor(v0, off, 64);
        v1 += __shfl_xor(v1, off, 64);
        v2 += __shfl_xor(v2, off, 64);
        v3 += __shfl_xor(v3, off, 64);
      }
      if (lane == 0)
        *(float4*)&head6[w][0] = make_float4(v0+hbias, v1+hbias, v2+hbias, v3+hbias);
    }
    __syncthreads();

    if (j < GBPB) {
      const int gb = b0 + j;
      const float p  = head6[0][j];
      const float m0 = head6[1][j];
      const float m1 = head6[2][j];
      const float l0 = head6[3][j];
      const float l1 = head6[4][j];
      const float cr = tanhf_(head6[5][j]);
      float* ob = out + ((size_t)t*1024 + gb)*6;
      *(float2*)(ob + 0) = make_float2(p,  m0);
      *(float2*)(ob + 2) = make_float2(m1, l0);
      *(float2*)(ob + 4) = make_float2(l1, cr);
      const float e0 = eps[(t*1024 + gb)*2 + 0];
      const float e1 = eps[(t*1024 + gb)*2 + 1];
      const float sx = fexp2(l0 * LOG2E);
      const float sy = fexp2(l1 * LOG2E);
      const float rt = sqrtf(fmaxf(1.f - cr*cr, 1e-12f));
      a_l[j][0] = fmaf(sx, e0, m0);
      a_l[j][1] = fmaf(sy, fmaf(cr, e0, rt*e1), m1);
    }
    __syncthreads();
  }
}

extern "C" void kernel_launch(void* const* d_in, const int* in_sizes, int n_in,
                              void* d_out, int out_size, void* d_ws, size_t ws_size,
                              hipStream_t stream) {
  const float* scene = (const float*)d_in[0];
  const float* eps   = (const float*)d_in[1];
  const float* nw_f  = (const float*)d_in[2];
  const float* nu_f  = (const float*)d_in[3];
  const float* nbi_f = (const float*)d_in[4];
  const float* nbh_f = (const float*)d_in[5];
  const float* nw_b  = (const float*)d_in[6];
  const float* nu_b  = (const float*)d_in[7];
  const float* nbi_b = (const float*)d_in[8];
  const float* nbh_b = (const float*)d_in[9];
  const float* ew_f  = (const float*)d_in[10];
  const float* eu_f  = (const float*)d_in[11];
  const float* ebi_f = (const float*)d_in[12];
  const float* ebh_f = (const float*)d_in[13];
  const float* ew_b  = (const float*)d_in[14];
  const float* eu_b  = (const float*)d_in[15];
  const float* ebi_b = (const float*)d_in[16];
  const float* ebh_b = (const float*)d_in[17];
  const float* gw    = (const float*)d_in[18];
  const float* gu    = (const float*)d_in[19];
  const float* gbi   = (const float*)d_in[20];
  const float* gbh   = (const float*)d_in[21];
  const float* aw    = (const float*)d_in[22];
  const float* ab    = (const float*)d_in[23];
  const float* sw    = (const float*)d_in[24];
  const float* sb    = (const float*)d_in[25];
  const float* pw    = (const float*)d_in[26];
  const float* pb    = (const float*)d_in[27];
  const float* mw    = (const float*)d_in[28];
  const float* mb    = (const float*)d_in[29];
  const float* lw    = (const float*)d_in[30];
  const float* lb    = (const float*)d_in[31];
  const float* cw    = (const float*)d_in[32];
  const float* cb    = (const float*)d_in[33];

  float* catted = (float*)d_ws;                           // 1024*180*4 = 737280 B
  float* a0p    = (float*)((char*)d_ws + 737280);         // 1024*2*4   =   8192 B
  float* pose2  = (float*)((char*)d_ws + 745472);         // 1024*2*4   =   8192 B

  scene_kernel<<<1024, 64, 0, stream>>>(scene, nw_f, nu_f, nbi_f, nbh_f,
                                        nw_b, nu_b, nbi_b, nbh_b, aw, ab,
                                        catted, a0p, pose2);
  edge_kernel<<<1024, 64, 0, stream>>>(scene, ew_f, eu_f, ebi_f, ebh_f,
                                       ew_b, eu_b, ebi_b, ebh_b, pose2, catted);
  gru_kernel<<<256, 384, 0, stream>>>(catted, a0p, eps, gw, gu, gbi, gbh,
                                      sw, sb, pw, pb, mw, mb, lw, lb, cw, cb,
                                      (float*)d_out);
}